// Round 3
// baseline (464.158 us; speedup 1.0000x reference)
//
#include <hip/hip_runtime.h>
#include <hip/hip_bf16.h>

#define NNODES 10000
#define FIN    256
#define HEADS  4
#define H1DIM  1024
#define FOUT   256
#define NEG    0.2f
#define GNEPS  1e-5f

typedef unsigned short u16;

__device__ __forceinline__ float bf2f(u16 u) {
    union { unsigned int i; float f; } v; v.i = ((unsigned int)u) << 16; return v.f;
}
__device__ __forceinline__ u16 f2bf(float f) {
    __hip_bfloat16 h = __float2bfloat16(f);
    union { __hip_bfloat16 h; u16 u; } v; v.h = h; return v.u;
}
__device__ __forceinline__ float lrelu(float v) { return v > 0.f ? v : NEG * v; }

// ---- dtype probes -------------------------------------------------------
// edge_index: int64 iff odd int32 words are all zero
__global__ void detect_ei_kernel(const int* __restrict__ ei, int* __restrict__ flag)
{
    int or_odd = ei[1] | ei[3] | ei[5] | ei[7] | ei[9] | ei[11];
    flag[0] = (or_odd == 0) ? 1 : 0;
}
// float arrays: bf16-packed iff even u16 words of x all look like sane bf16
__global__ void detect_f_kernel(const u16* __restrict__ x, int* __restrict__ fflag)
{
    int sane = 1;
    for (int i = 0; i < 32; i += 2) {
        u16 w = x[i];
        int e = (w >> 7) & 0xFF;
        if (!(w == 0 || w == 0x8000 || (e >= 100 && e <= 150))) sane = 0;
    }
    fflag[0] = sane;   // 1 = bf16 inputs, 0 = fp32 inputs
}

// ---- convert all float inputs to fp32 workspace copies ------------------
struct CvtDesc { const void* src; float* dst; int n; };
struct CvtTable { CvtDesc d[12]; };

__global__ void convert_kernel(CvtTable tab, const int* __restrict__ fflag)
{
    CvtDesc d = tab.d[blockIdx.y];
    int i4 = (blockIdx.x * blockDim.x + threadIdx.x) * 4;
    if (i4 >= d.n) return;
    if (fflag[0]) {
        ushort4 u = *reinterpret_cast<const ushort4*>((const u16*)d.src + i4);
        float4 o = make_float4(bf2f(u.x), bf2f(u.y), bf2f(u.z), bf2f(u.w));
        *reinterpret_cast<float4*>(d.dst + i4) = o;
    } else {
        *reinterpret_cast<float4*>(d.dst + i4) =
            *reinterpret_cast<const float4*>((const float*)d.src + i4);
    }
}

// ---- GEMM: C[M,N] = A[M,K] @ B[K,N]fp32; A bf16 or fp32 (template) ------
// 64x64 tile, 16x16 threads, 4x4 per thread, BK=16
template<bool ABF16>
__global__ void gemm_kernel(const void* __restrict__ Av, const float* __restrict__ B,
                            float* __restrict__ C, u16* __restrict__ Cb,
                            int M, int N, int K)
{
    __shared__ float As[16][64];
    __shared__ float Bs[16][64];
    const int tx = threadIdx.x, ty = threadIdx.y;
    const int tid = ty * 16 + tx;
    const int n0 = blockIdx.x * 64;
    const int m0 = blockIdx.y * 64;

    float acc[4][4];
#pragma unroll
    for (int i = 0; i < 4; i++)
#pragma unroll
        for (int j = 0; j < 4; j++) acc[i][j] = 0.f;

    const int aIdx = tid * 4;
    const int am = aIdx >> 4;          // 0..63
    const int ak = aIdx & 15;          // 0,4,8,12
    const int bIdx = tid * 4;
    const int bk = bIdx >> 6;          // 0..15
    const int bn = bIdx & 63;          // 0,4,..,60

    for (int kt = 0; kt < K; kt += 16) {
        {
            int row = m0 + am;
            float4 v = make_float4(0.f, 0.f, 0.f, 0.f);
            if (row < M) {
                if (ABF16) {
                    ushort4 u = *reinterpret_cast<const ushort4*>((const u16*)Av + (size_t)row * K + kt + ak);
                    v = make_float4(bf2f(u.x), bf2f(u.y), bf2f(u.z), bf2f(u.w));
                } else {
                    v = *reinterpret_cast<const float4*>((const float*)Av + (size_t)row * K + kt + ak);
                }
            }
            As[ak + 0][am] = v.x;
            As[ak + 1][am] = v.y;
            As[ak + 2][am] = v.z;
            As[ak + 3][am] = v.w;
        }
        {
            float4 v = *reinterpret_cast<const float4*>(B + (size_t)(kt + bk) * N + n0 + bn);
            Bs[bk][bn + 0] = v.x;
            Bs[bk][bn + 1] = v.y;
            Bs[bk][bn + 2] = v.z;
            Bs[bk][bn + 3] = v.w;
        }
        __syncthreads();
#pragma unroll
        for (int kk = 0; kk < 16; kk++) {
            float a0 = As[kk][ty * 4 + 0], a1 = As[kk][ty * 4 + 1];
            float a2 = As[kk][ty * 4 + 2], a3 = As[kk][ty * 4 + 3];
            float b0 = Bs[kk][tx * 4 + 0], b1 = Bs[kk][tx * 4 + 1];
            float b2 = Bs[kk][tx * 4 + 2], b3 = Bs[kk][tx * 4 + 3];
            acc[0][0] += a0 * b0; acc[0][1] += a0 * b1; acc[0][2] += a0 * b2; acc[0][3] += a0 * b3;
            acc[1][0] += a1 * b0; acc[1][1] += a1 * b1; acc[1][2] += a1 * b2; acc[1][3] += a1 * b3;
            acc[2][0] += a2 * b0; acc[2][1] += a2 * b1; acc[2][2] += a2 * b2; acc[2][3] += a2 * b3;
            acc[3][0] += a3 * b0; acc[3][1] += a3 * b1; acc[3][2] += a3 * b2; acc[3][3] += a3 * b3;
        }
        __syncthreads();
    }

#pragma unroll
    for (int i = 0; i < 4; i++) {
        int row = m0 + ty * 4 + i;
        if (row >= M) continue;
        int col = n0 + tx * 4;
        if (C) {
            float4 o = make_float4(acc[i][0], acc[i][1], acc[i][2], acc[i][3]);
            *reinterpret_cast<float4*>(C + (size_t)row * N + col) = o;
        }
        if (Cb) {
            ushort4 o;
            o.x = f2bf(acc[i][0]); o.y = f2bf(acc[i][1]);
            o.z = f2bf(acc[i][2]); o.w = f2bf(acc[i][3]);
            *reinterpret_cast<ushort4*>(Cb + (size_t)row * N + col) = o;
        }
    }
}

// ---- attention projections layer 1 (h1 bf16, att fp32) ------------------
__global__ void al1_kernel(const u16* __restrict__ h1, const float* __restrict__ as,
                           const float* __restrict__ ad, float* __restrict__ als,
                           float* __restrict__ ald)
{
    int n = blockIdx.x;
    int t = threadIdx.x;          // 256; channels 4t..4t+3; head = t/64
    int c = t * 4;
    ushort4 hv = *reinterpret_cast<const ushort4*>(h1 + (size_t)n * H1DIM + c);
    float4 av = *reinterpret_cast<const float4*>(as + c);
    float4 dv = *reinterpret_cast<const float4*>(ad + c);
    float h0 = bf2f(hv.x), h1v = bf2f(hv.y), h2v = bf2f(hv.z), h3v = bf2f(hv.w);
    float ps = h0 * av.x + h1v * av.y + h2v * av.z + h3v * av.w;
    float pd = h0 * dv.x + h1v * dv.y + h2v * dv.z + h3v * dv.w;
#pragma unroll
    for (int off = 32; off > 0; off >>= 1) {
        ps += __shfl_down(ps, off, 64);
        pd += __shfl_down(pd, off, 64);
    }
    if ((t & 63) == 0) {
        int hd = t >> 6;
        als[n * HEADS + hd] = ps;
        ald[n * HEADS + hd] = pd;
    }
}

// ---- attention projections layer 2 (H=1), h2 fp32 -----------------------
__global__ void al2_kernel(const float* __restrict__ h2, const float* __restrict__ as,
                           const float* __restrict__ ad, float* __restrict__ als,
                           float* __restrict__ ald)
{
    int n = blockIdx.x;
    int t = threadIdx.x;          // 64 threads, 4 channels each
    int c = t * 4;
    float4 v = *reinterpret_cast<const float4*>(h2 + (size_t)n * FOUT + c);
    float4 av = *reinterpret_cast<const float4*>(as + c);
    float4 dv = *reinterpret_cast<const float4*>(ad + c);
    float ps = v.x * av.x + v.y * av.y + v.z * av.z + v.w * av.w;
    float pd = v.x * dv.x + v.y * dv.y + v.z * dv.z + v.w * dv.w;
#pragma unroll
    for (int off = 32; off > 0; off >>= 1) {
        ps += __shfl_down(ps, off, 64);
        pd += __shfl_down(pd, off, 64);
    }
    if (t == 0) { als[n] = ps; ald[n] = pd; }
}

// ---- CSR build ----------------------------------------------------------
__global__ void hist_kernel(const int* __restrict__ ei, int NE, int Etot,
                            const int* __restrict__ flag, int* __restrict__ deg)
{
    int e = blockIdx.x * blockDim.x + threadIdx.x;
    if (e >= Etot) return;
    int is64 = flag[0];
    int dst;
    if (e < NE) dst = is64 ? ei[2 * (NE + e)] : ei[NE + e];
    else        dst = e - NE;
    if ((unsigned)dst >= NNODES) return;
    atomicAdd(&deg[dst], 1);
}

__global__ void scan_kernel(const int* __restrict__ deg, int* __restrict__ offs)
{
    __shared__ int part[256];
    const int N = NNODES;
    const int chunk = 40;       // 256*40 = 10240 >= 10001
    int t = threadIdx.x;
    int start = t * chunk;
    int s = 0;
    for (int i = 0; i < chunk; i++) { int idx = start + i; if (idx < N) s += deg[idx]; }
    part[t] = s;
    __syncthreads();
    for (int d = 1; d < 256; d <<= 1) {
        int v = (t >= d) ? part[t - d] : 0;
        __syncthreads();
        part[t] += v;
        __syncthreads();
    }
    int run = (t > 0) ? part[t - 1] : 0;
    for (int i = 0; i < chunk; i++) {
        int idx = start + i;
        if (idx <= N) offs[idx] = run;
        if (idx < N)  run += deg[idx];
    }
}

__global__ void scatter_kernel(const int* __restrict__ ei, int NE, int Etot,
                               const int* __restrict__ flag,
                               const int* __restrict__ offs, int* __restrict__ cursor,
                               int* __restrict__ ssort)
{
    int e = blockIdx.x * blockDim.x + threadIdx.x;
    if (e >= Etot) return;
    int is64 = flag[0];
    int src, dst;
    if (e < NE) {
        src = is64 ? ei[2 * e] : ei[e];
        dst = is64 ? ei[2 * (NE + e)] : ei[NE + e];
    } else {
        src = dst = e - NE;
    }
    if ((unsigned)dst >= NNODES) return;
    if ((unsigned)src >= NNODES) src = 0;
    int pos = offs[dst] + atomicAdd(&cursor[dst], 1);
    ssort[pos] = src;
}

// ---- layer-1 aggregation, one block per dst; bf16 out -------------------
__global__ void agg1_kernel(const int* __restrict__ offs, const int* __restrict__ ssort,
                            const float* __restrict__ als, const float* __restrict__ ald,
                            const u16* __restrict__ h1, const float* __restrict__ b1,
                            u16* __restrict__ out1)
{
    int n = blockIdx.x;
    int t = threadIdx.x;           // 256; channels 4t..4t+3; head = t/64
    int hd = t >> 6;
    int c = t * 4;
    int e0 = offs[n], e1 = offs[n + 1];
    float adv = ald[n * HEADS + hd];

    float m = -1e30f;
    for (int e = e0; e < e1; e++) {
        int s = ssort[e];
        float v = lrelu(als[s * HEADS + hd] + adv);
        m = fmaxf(m, v);
    }
    float denom = 0.f, a0 = 0.f, a1 = 0.f, a2 = 0.f, a3 = 0.f;
    for (int e = e0; e < e1; e++) {
        int s = ssort[e];
        float v = lrelu(als[s * HEADS + hd] + adv);
        float w = __expf(v - m);
        denom += w;
        ushort4 hv = *reinterpret_cast<const ushort4*>(h1 + (size_t)s * H1DIM + c);
        a0 += w * bf2f(hv.x); a1 += w * bf2f(hv.y);
        a2 += w * bf2f(hv.z); a3 += w * bf2f(hv.w);
    }
    float inv = (denom > 0.f) ? 1.0f / denom : 0.f;
    float4 bv = *reinterpret_cast<const float4*>(b1 + c);
    ushort4 o;
    o.x = f2bf(a0 * inv + bv.x);
    o.y = f2bf(a1 * inv + bv.y);
    o.z = f2bf(a2 * inv + bv.z);
    o.w = f2bf(a3 * inv + bv.w);
    *reinterpret_cast<ushort4*>(out1 + (size_t)n * H1DIM + c) = o;
}

// ---- GraphNorm stats (bf16 input) ---------------------------------------
__global__ void stats_kernel(const u16* __restrict__ out1, float* __restrict__ gsum,
                             float* __restrict__ gsum2)
{
    int t = threadIdx.x;       // 256; 4 channels each
    int c = t * 4;
    int r0 = blockIdx.x * 64;
    float s0 = 0, s1 = 0, s2 = 0, s3 = 0, q0 = 0, q1 = 0, q2 = 0, q3 = 0;
    for (int i = 0; i < 64; i++) {
        int r = r0 + i;
        if (r >= NNODES) break;
        ushort4 u = *reinterpret_cast<const ushort4*>(out1 + (size_t)r * H1DIM + c);
        float vx = bf2f(u.x), vy = bf2f(u.y), vz = bf2f(u.z), vw = bf2f(u.w);
        s0 += vx; q0 += vx * vx;
        s1 += vy; q1 += vy * vy;
        s2 += vz; q2 += vz * vz;
        s3 += vw; q3 += vw * vw;
    }
    atomicAdd(&gsum[c + 0], s0); atomicAdd(&gsum2[c + 0], q0);
    atomicAdd(&gsum[c + 1], s1); atomicAdd(&gsum2[c + 1], q1);
    atomicAdd(&gsum[c + 2], s2); atomicAdd(&gsum2[c + 2], q2);
    atomicAdd(&gsum[c + 3], s3); atomicAdd(&gsum2[c + 3], q3);
}

__global__ void norm_params_kernel(const float* __restrict__ gsum, const float* __restrict__ gsum2,
                                   const float* __restrict__ w, const float* __restrict__ b,
                                   const float* __restrict__ ms, float* __restrict__ scale,
                                   float* __restrict__ shift)
{
    int c = blockIdx.x * blockDim.x + threadIdx.x;
    if (c >= H1DIM) return;
    const float invN = 1.0f / (float)NNODES;
    float mean = gsum[c] * invN;
    float ex2  = gsum2[c] * invN;
    float msv  = ms[c];
    float var  = ex2 - 2.f * msv * mean * mean + msv * msv * mean * mean;
    float sc   = w[c] * rsqrtf(fmaxf(var, 0.f) + GNEPS);
    scale[c] = sc;
    shift[c] = b[c] - sc * msv * mean;
}

// ---- in-place: out1 = bf16(relu(scale*out1+shift)) ----------------------
__global__ void hn_kernel(u16* __restrict__ out1, const float* __restrict__ scale,
                          const float* __restrict__ shift)
{
    int i = blockIdx.x * blockDim.x + threadIdx.x;
    size_t idx = (size_t)i * 4;
    if (idx >= (size_t)NNODES * H1DIM) return;
    int c = (int)(idx & (H1DIM - 1));
    ushort4 u  = *reinterpret_cast<const ushort4*>(out1 + idx);
    float4 sc = *reinterpret_cast<const float4*>(scale + c);
    float4 sh = *reinterpret_cast<const float4*>(shift + c);
    ushort4 o;
    o.x = f2bf(fmaxf(0.f, bf2f(u.x) * sc.x + sh.x));
    o.y = f2bf(fmaxf(0.f, bf2f(u.y) * sc.y + sh.y));
    o.z = f2bf(fmaxf(0.f, bf2f(u.z) * sc.z + sh.z));
    o.w = f2bf(fmaxf(0.f, bf2f(u.w) * sc.w + sh.w));
    *reinterpret_cast<ushort4*>(out1 + idx) = o;
}

// ---- layer-2 aggregation, one wave per dst; dual-dtype output -----------
__global__ void agg2_kernel(const int* __restrict__ offs, const int* __restrict__ ssort,
                            const float* __restrict__ als, const float* __restrict__ ald,
                            const float* __restrict__ h2, const float* __restrict__ b2,
                            const int* __restrict__ fflag, void* __restrict__ outv)
{
    int n = blockIdx.x;
    int t = threadIdx.x;       // 64; 4 channels each
    int c = t * 4;
    int e0 = offs[n], e1 = offs[n + 1];
    float adv = ald[n];

    float m = -1e30f;
    for (int e = e0; e < e1; e++) {
        int s = ssort[e];
        float v = lrelu(als[s] + adv);
        m = fmaxf(m, v);
    }
    float denom = 0.f, a0 = 0.f, a1 = 0.f, a2 = 0.f, a3 = 0.f;
    for (int e = e0; e < e1; e++) {
        int s = ssort[e];
        float v = lrelu(als[s] + adv);
        float w = __expf(v - m);
        denom += w;
        float4 hv = *reinterpret_cast<const float4*>(h2 + (size_t)s * FOUT + c);
        a0 += w * hv.x; a1 += w * hv.y; a2 += w * hv.z; a3 += w * hv.w;
    }
    float inv = (denom > 0.f) ? 1.0f / denom : 0.f;
    float4 bv = *reinterpret_cast<const float4*>(b2 + c);
    float r0 = a0 * inv + bv.x;
    float r1 = a1 * inv + bv.y;
    float r2 = a2 * inv + bv.z;
    float r3 = a3 * inv + bv.w;
    if (fflag[0]) {
        ushort4 o;
        o.x = f2bf(r0); o.y = f2bf(r1); o.z = f2bf(r2); o.w = f2bf(r3);
        *reinterpret_cast<ushort4*>((u16*)outv + (size_t)n * FOUT + c) = o;
    } else {
        float4 o = make_float4(r0, r1, r2, r3);
        *reinterpret_cast<float4*>((float*)outv + (size_t)n * FOUT + c) = o;
    }
}

// =========================================================================
extern "C" void kernel_launch(void* const* d_in, const int* in_sizes, int n_in,
                              void* d_out, int out_size, void* d_ws, size_t ws_size,
                              hipStream_t stream)
{
    const void* x    = d_in[0];
    const int*  ei   = (const int*)d_in[1];
    const void* W1   = d_in[2];
    const void* as1  = d_in[3];
    const void* ad1  = d_in[4];
    const void* b1   = d_in[5];
    const void* gnw  = d_in[6];
    const void* gnb  = d_in[7];
    const void* gnms = d_in[8];
    const void* W2   = d_in[9];
    const void* as2  = d_in[10];
    const void* ad2  = d_in[11];
    const void* b2   = d_in[12];

    const int NE   = in_sizes[1] / 2;       // 160000
    const int Etot = NE + NNODES;           // 170000

    // ---- workspace carve (256B aligned), total ~55 MB ----
    char* w = (char*)d_ws;
    size_t off = 0;
    auto carve = [&](size_t bytes) -> char* {
        char* p = w + off;
        off = (off + bytes + 255) & ~(size_t)255;
        return p;
    };
    int*   deg    = (int*)carve((size_t)NNODES * 4);
    int*   cursor = (int*)carve((size_t)NNODES * 4);
    float* gsum   = (float*)carve(1024 * 4);
    float* gsum2  = (float*)carve(1024 * 4);
    size_t zero_bytes = off;                        // memset-0 region
    int*   flag   = (int*)carve(256);               // [0]=ei is64
    int*   fflag  = (int*)carve(256);               // [0]=float inputs are bf16
    int*   offs   = (int*)carve((size_t)(NNODES + 1) * 4);
    int*   ssort  = (int*)carve((size_t)Etot * 4);
    u16*   h1buf  = (u16*)carve((size_t)NNODES * H1DIM * 2);   // h1 bf16; reused as h2 fp32
    u16*   out1b  = (u16*)carve((size_t)NNODES * H1DIM * 2);   // agg1 out bf16; normalized in place
    float* al1s   = (float*)carve((size_t)NNODES * HEADS * 4);
    float* al1d   = (float*)carve((size_t)NNODES * HEADS * 4);
    float* al2s   = (float*)carve((size_t)NNODES * 4);
    float* al2d   = (float*)carve((size_t)NNODES * 4);
    float* scale  = (float*)carve(1024 * 4);
    float* shift  = (float*)carve(1024 * 4);
    // fp32 canonical copies of the float inputs
    float* xf    = (float*)carve((size_t)NNODES * FIN * 4);    // 10.24 MB
    float* W1f   = (float*)carve((size_t)FIN * H1DIM * 4);     // 1.05 MB
    float* as1f  = (float*)carve(1024 * 4);
    float* ad1f  = (float*)carve(1024 * 4);
    float* b1f   = (float*)carve(1024 * 4);
    float* gnwf  = (float*)carve(1024 * 4);
    float* gnbf  = (float*)carve(1024 * 4);
    float* gnmsf = (float*)carve(1024 * 4);
    float* W2f   = (float*)carve((size_t)H1DIM * FOUT * 4);    // 1.05 MB
    float* as2f  = (float*)carve(256 * 4);
    float* ad2f  = (float*)carve(256 * 4);
    float* b2f   = (float*)carve(256 * 4);
    (void)ws_size;

    float* h2 = (float*)h1buf;      // reuse: h1 dead after agg1 (fp32 [N,256] = 10.24MB <= 20.5MB)

    hipMemsetAsync(d_ws, 0, zero_bytes, stream);
    detect_ei_kernel<<<1, 1, 0, stream>>>(ei, flag);
    detect_f_kernel<<<1, 1, 0, stream>>>((const u16*)x, fflag);

    // convert all 12 float arrays to fp32
    {
        CvtTable tab;
        tab.d[0]  = { x,    xf,    NNODES * FIN };
        tab.d[1]  = { W1,   W1f,   FIN * H1DIM };
        tab.d[2]  = { as1,  as1f,  H1DIM };
        tab.d[3]  = { ad1,  ad1f,  H1DIM };
        tab.d[4]  = { b1,   b1f,   H1DIM };
        tab.d[5]  = { gnw,  gnwf,  H1DIM };
        tab.d[6]  = { gnb,  gnbf,  H1DIM };
        tab.d[7]  = { gnms, gnmsf, H1DIM };
        tab.d[8]  = { W2,   W2f,   H1DIM * FOUT };
        tab.d[9]  = { as2,  as2f,  FOUT };
        tab.d[10] = { ad2,  ad2f,  FOUT };
        tab.d[11] = { b2,   b2f,   FOUT };
        dim3 grd((NNODES * FIN / 4 + 255) / 256, 12);
        convert_kernel<<<grd, 256, 0, stream>>>(tab, fflag);
    }

    // CSR build
    {
        int nb = (Etot + 255) / 256;
        hist_kernel<<<nb, 256, 0, stream>>>(ei, NE, Etot, flag, deg);
        scan_kernel<<<1, 256, 0, stream>>>(deg, offs);
        scatter_kernel<<<nb, 256, 0, stream>>>(ei, NE, Etot, flag, offs, cursor, ssort);
    }

    // layer 1: h1 = x @ W1  (bf16 out)
    {
        dim3 blk(16, 16);
        dim3 grd(H1DIM / 64, (NNODES + 63) / 64);
        gemm_kernel<false><<<grd, blk, 0, stream>>>(xf, W1f, nullptr, h1buf, NNODES, H1DIM, FIN);
    }
    al1_kernel<<<NNODES, 256, 0, stream>>>(h1buf, as1f, ad1f, al1s, al1d);
    agg1_kernel<<<NNODES, 256, 0, stream>>>(offs, ssort, al1s, al1d, h1buf, b1f, out1b);

    // GraphNorm + ReLU (in place on out1b)
    stats_kernel<<<(NNODES + 63) / 64, 256, 0, stream>>>(out1b, gsum, gsum2);
    norm_params_kernel<<<(H1DIM + 255) / 256, 256, 0, stream>>>(gsum, gsum2, gnwf, gnbf, gnmsf, scale, shift);
    hn_kernel<<<(NNODES * H1DIM / 4 + 255) / 256, 256, 0, stream>>>(out1b, scale, shift);

    // layer 2: h2 = hn @ W2 (fp32 out, into h1buf region)
    {
        dim3 blk(16, 16);
        dim3 grd(FOUT / 64, (NNODES + 63) / 64);
        gemm_kernel<true><<<grd, blk, 0, stream>>>(out1b, W2f, h2, nullptr, NNODES, FOUT, H1DIM);
    }
    al2_kernel<<<NNODES, 64, 0, stream>>>(h2, as2f, ad2f, al2s, al2d);
    agg2_kernel<<<NNODES, 64, 0, stream>>>(offs, ssort, al2s, al2d, h2, b2f, fflag, d_out);
}

// Round 4
// 338.319 us; speedup vs baseline: 1.3720x; 1.3720x over previous
//
#include <hip/hip_runtime.h>
#include <hip/hip_bf16.h>

#define NNODES 10000
#define FIN    256
#define HEADS  4
#define H1DIM  1024
#define FOUT   256
#define NEG    0.2f
#define GNEPS  1e-5f

typedef unsigned short u16;
typedef __attribute__((ext_vector_type(8))) short bf16x8;
typedef __attribute__((ext_vector_type(4))) float f32x4;

__device__ __forceinline__ float bf2f(u16 u) {
    union { unsigned int i; float f; } v; v.i = ((unsigned int)u) << 16; return v.f;
}
__device__ __forceinline__ u16 f2bf(float f) {
    __hip_bfloat16 h = __float2bfloat16(f);
    union { __hip_bfloat16 h; u16 u; } v; v.h = h; return v.u;
}
__device__ __forceinline__ float lrelu(float v) { return v > 0.f ? v : NEG * v; }

// ---- dtype probes -------------------------------------------------------
__global__ void detect_ei_kernel(const int* __restrict__ ei, int* __restrict__ flag)
{
    int or_odd = ei[1] | ei[3] | ei[5] | ei[7] | ei[9] | ei[11];
    flag[0] = (or_odd == 0) ? 1 : 0;
}
__global__ void detect_f_kernel(const u16* __restrict__ x, int* __restrict__ fflag)
{
    int sane = 1;
    for (int i = 0; i < 32; i += 2) {
        u16 w = x[i];
        int e = (w >> 7) & 0xFF;
        if (!(w == 0 || w == 0x8000 || (e >= 100 && e <= 150))) sane = 0;
    }
    fflag[0] = sane;   // 1 = bf16 inputs, 0 = fp32 inputs
}

// ---- small fp32 conversions --------------------------------------------
struct CvtDesc { const void* src; float* dst; int n; };
struct CvtTable { CvtDesc d[9]; };

__global__ void convert_small_kernel(CvtTable tab, const int* __restrict__ fflag)
{
    CvtDesc d = tab.d[blockIdx.y];
    int i4 = (blockIdx.x * blockDim.x + threadIdx.x) * 4;
    if (i4 >= d.n) return;
    if (fflag[0]) {
        ushort4 u = *reinterpret_cast<const ushort4*>((const u16*)d.src + i4);
        *reinterpret_cast<float4*>(d.dst + i4) =
            make_float4(bf2f(u.x), bf2f(u.y), bf2f(u.z), bf2f(u.w));
    } else {
        *reinterpret_cast<float4*>(d.dst + i4) =
            *reinterpret_cast<const float4*>((const float*)d.src + i4);
    }
}

// ---- x -> bf16 [M,K] ----------------------------------------------------
__global__ void cvt_x_kernel(const void* __restrict__ src, u16* __restrict__ dst,
                             int n, const int* __restrict__ fflag)
{
    int i4 = (blockIdx.x * blockDim.x + threadIdx.x) * 4;
    if (i4 >= n) return;
    if (fflag[0]) {
        *reinterpret_cast<ushort4*>(dst + i4) =
            *reinterpret_cast<const ushort4*>((const u16*)src + i4);
    } else {
        float4 v = *reinterpret_cast<const float4*>((const float*)src + i4);
        ushort4 o; o.x = f2bf(v.x); o.y = f2bf(v.y); o.z = f2bf(v.z); o.w = f2bf(v.w);
        *reinterpret_cast<ushort4*>(dst + i4) = o;
    }
}

// ---- W [K,N] -> Wt bf16 [N,K] ------------------------------------------
__global__ void cvt_wt_kernel(const void* __restrict__ src, u16* __restrict__ dst,
                              int K, int N, const int* __restrict__ fflag)
{
    int i = blockIdx.x * blockDim.x + threadIdx.x;   // over K*N, n fast
    if (i >= K * N) return;
    int k = i / N, n = i - k * N;
    u16 o;
    if (fflag[0]) o = ((const u16*)src)[i];
    else          o = f2bf(((const float*)src)[i]);
    dst[(size_t)n * K + k] = o;
}

// ---- MFMA GEMM: C[M,N]bf16 = A[M,K]bf16 @ Bt[N,K]bf16^T -----------------
// 128x128 tile, 256 threads = 4 waves (2x2), each wave 64x64 via 4x4 MFMA 16x16x32
#define LDS_STRIDE 40   // bf16 units; 80 B rows: 16B-aligned, <=2-way banks
__global__ void __launch_bounds__(256, 2)
mfma_gemm_kernel(const u16* __restrict__ A, const u16* __restrict__ Bt,
                 u16* __restrict__ C, int M, int N, int K)
{
    __shared__ u16 Alds[128 * LDS_STRIDE];
    __shared__ u16 Blds[128 * LDS_STRIDE];

    const int tid  = threadIdx.x;
    const int lane = tid & 63;
    const int wave = tid >> 6;
    const int wm = wave >> 1, wn = wave & 1;
    const int l15 = lane & 15, quad = lane >> 4;
    const int n0 = blockIdx.x * 128;
    const int m0 = blockIdx.y * 128;

    f32x4 acc[4][4];
#pragma unroll
    for (int i = 0; i < 4; i++)
#pragma unroll
        for (int j = 0; j < 4; j++) acc[i][j] = (f32x4){0.f, 0.f, 0.f, 0.f};

    for (int kt = 0; kt < K; kt += 32) {
        __syncthreads();
        // stage A and Bt: 128 rows x 32 k each; 512 groups of 8 bf16; 2 rounds
#pragma unroll
        for (int i = 0; i < 2; i++) {
            int idx8 = i * 256 + tid;          // 0..511
            int row  = idx8 >> 2;              // 0..127
            int col  = (idx8 & 3) * 8;         // 0,8,16,24
            int gr = m0 + row;
            uint4 av = make_uint4(0u, 0u, 0u, 0u);
            if (gr < M) av = *reinterpret_cast<const uint4*>(A + (size_t)gr * K + kt + col);
            *reinterpret_cast<uint4*>(&Alds[row * LDS_STRIDE + col]) = av;
            uint4 bv = *reinterpret_cast<const uint4*>(Bt + (size_t)(n0 + row) * K + kt + col);
            *reinterpret_cast<uint4*>(&Blds[row * LDS_STRIDE + col]) = bv;
        }
        __syncthreads();

        bf16x8 a_frag[4], b_frag[4];
#pragma unroll
        for (int mi = 0; mi < 4; mi++)
            a_frag[mi] = *reinterpret_cast<const bf16x8*>(
                &Alds[(wm * 64 + mi * 16 + l15) * LDS_STRIDE + quad * 8]);
#pragma unroll
        for (int ni = 0; ni < 4; ni++)
            b_frag[ni] = *reinterpret_cast<const bf16x8*>(
                &Blds[(wn * 64 + ni * 16 + l15) * LDS_STRIDE + quad * 8]);
#pragma unroll
        for (int mi = 0; mi < 4; mi++)
#pragma unroll
            for (int ni = 0; ni < 4; ni++)
                acc[mi][ni] = __builtin_amdgcn_mfma_f32_16x16x32_bf16(
                    a_frag[mi], b_frag[ni], acc[mi][ni], 0, 0, 0);
    }

    // epilogue: C/D layout col=lane&15, row=quad*4+reg
#pragma unroll
    for (int mi = 0; mi < 4; mi++) {
#pragma unroll
        for (int r = 0; r < 4; r++) {
            int row = m0 + wm * 64 + mi * 16 + quad * 4 + r;
            if (row >= M) continue;
#pragma unroll
            for (int ni = 0; ni < 4; ni++) {
                int col = n0 + wn * 64 + ni * 16 + l15;
                C[(size_t)row * N + col] = f2bf(acc[mi][ni][r]);
            }
        }
    }
}

// ---- attention projections layer 1 (h1 bf16) ----------------------------
__global__ void al1_kernel(const u16* __restrict__ h1, const float* __restrict__ as,
                           const float* __restrict__ ad, float* __restrict__ als,
                           float* __restrict__ ald)
{
    int n = blockIdx.x;
    int t = threadIdx.x;          // 256; channels 4t..4t+3; head = t/64
    int c = t * 4;
    ushort4 hv = *reinterpret_cast<const ushort4*>(h1 + (size_t)n * H1DIM + c);
    float4 av = *reinterpret_cast<const float4*>(as + c);
    float4 dv = *reinterpret_cast<const float4*>(ad + c);
    float h0 = bf2f(hv.x), h1v = bf2f(hv.y), h2v = bf2f(hv.z), h3v = bf2f(hv.w);
    float ps = h0 * av.x + h1v * av.y + h2v * av.z + h3v * av.w;
    float pd = h0 * dv.x + h1v * dv.y + h2v * dv.z + h3v * dv.w;
#pragma unroll
    for (int off = 32; off > 0; off >>= 1) {
        ps += __shfl_down(ps, off, 64);
        pd += __shfl_down(pd, off, 64);
    }
    if ((t & 63) == 0) {
        int hd = t >> 6;
        als[n * HEADS + hd] = ps;
        ald[n * HEADS + hd] = pd;
    }
}

// ---- attention projections layer 2 (H=1), h2 bf16 -----------------------
__global__ void al2_kernel(const u16* __restrict__ h2, const float* __restrict__ as,
                           const float* __restrict__ ad, float* __restrict__ als,
                           float* __restrict__ ald)
{
    int n = blockIdx.x;
    int t = threadIdx.x;          // 64 threads, 4 channels each
    int c = t * 4;
    ushort4 u = *reinterpret_cast<const ushort4*>(h2 + (size_t)n * FOUT + c);
    float4 av = *reinterpret_cast<const float4*>(as + c);
    float4 dv = *reinterpret_cast<const float4*>(ad + c);
    float v0 = bf2f(u.x), v1 = bf2f(u.y), v2 = bf2f(u.z), v3 = bf2f(u.w);
    float ps = v0 * av.x + v1 * av.y + v2 * av.z + v3 * av.w;
    float pd = v0 * dv.x + v1 * dv.y + v2 * dv.z + v3 * dv.w;
#pragma unroll
    for (int off = 32; off > 0; off >>= 1) {
        ps += __shfl_down(ps, off, 64);
        pd += __shfl_down(pd, off, 64);
    }
    if (t == 0) { als[n] = ps; ald[n] = pd; }
}

// ---- CSR build ----------------------------------------------------------
__global__ void hist_kernel(const int* __restrict__ ei, int NE, int Etot,
                            const int* __restrict__ flag, int* __restrict__ deg)
{
    int e = blockIdx.x * blockDim.x + threadIdx.x;
    if (e >= Etot) return;
    int is64 = flag[0];
    int dst;
    if (e < NE) dst = is64 ? ei[2 * (NE + e)] : ei[NE + e];
    else        dst = e - NE;
    if ((unsigned)dst >= NNODES) return;
    atomicAdd(&deg[dst], 1);
}

__global__ void scan_kernel(const int* __restrict__ deg, int* __restrict__ offs)
{
    __shared__ int part[256];
    const int N = NNODES;
    const int chunk = 40;       // 256*40 = 10240 >= 10001
    int t = threadIdx.x;
    int start = t * chunk;
    int s = 0;
    for (int i = 0; i < chunk; i++) { int idx = start + i; if (idx < N) s += deg[idx]; }
    part[t] = s;
    __syncthreads();
    for (int d = 1; d < 256; d <<= 1) {
        int v = (t >= d) ? part[t - d] : 0;
        __syncthreads();
        part[t] += v;
        __syncthreads();
    }
    int run = (t > 0) ? part[t - 1] : 0;
    for (int i = 0; i < chunk; i++) {
        int idx = start + i;
        if (idx <= N) offs[idx] = run;
        if (idx < N)  run += deg[idx];
    }
}

__global__ void scatter_kernel(const int* __restrict__ ei, int NE, int Etot,
                               const int* __restrict__ flag,
                               const int* __restrict__ offs, int* __restrict__ cursor,
                               int* __restrict__ ssort)
{
    int e = blockIdx.x * blockDim.x + threadIdx.x;
    if (e >= Etot) return;
    int is64 = flag[0];
    int src, dst;
    if (e < NE) {
        src = is64 ? ei[2 * e] : ei[e];
        dst = is64 ? ei[2 * (NE + e)] : ei[NE + e];
    } else {
        src = dst = e - NE;
    }
    if ((unsigned)dst >= NNODES) return;
    if ((unsigned)src >= NNODES) src = 0;
    int pos = offs[dst] + atomicAdd(&cursor[dst], 1);
    ssort[pos] = src;
}

// ---- layer-1 aggregation, one block per dst; bf16 out -------------------
__global__ void agg1_kernel(const int* __restrict__ offs, const int* __restrict__ ssort,
                            const float* __restrict__ als, const float* __restrict__ ald,
                            const u16* __restrict__ h1, const float* __restrict__ b1,
                            u16* __restrict__ out1)
{
    int n = blockIdx.x;
    int t = threadIdx.x;           // 256; channels 4t..4t+3; head = t/64
    int hd = t >> 6;
    int c = t * 4;
    int e0 = offs[n], e1 = offs[n + 1];
    float adv = ald[n * HEADS + hd];

    float m = -1e30f;
    for (int e = e0; e < e1; e++) {
        int s = ssort[e];
        float v = lrelu(als[s * HEADS + hd] + adv);
        m = fmaxf(m, v);
    }
    float denom = 0.f, a0 = 0.f, a1 = 0.f, a2 = 0.f, a3 = 0.f;
    for (int e = e0; e < e1; e++) {
        int s = ssort[e];
        float v = lrelu(als[s * HEADS + hd] + adv);
        float w = __expf(v - m);
        denom += w;
        ushort4 hv = *reinterpret_cast<const ushort4*>(h1 + (size_t)s * H1DIM + c);
        a0 += w * bf2f(hv.x); a1 += w * bf2f(hv.y);
        a2 += w * bf2f(hv.z); a3 += w * bf2f(hv.w);
    }
    float inv = (denom > 0.f) ? 1.0f / denom : 0.f;
    float4 bv = *reinterpret_cast<const float4*>(b1 + c);
    ushort4 o;
    o.x = f2bf(a0 * inv + bv.x);
    o.y = f2bf(a1 * inv + bv.y);
    o.z = f2bf(a2 * inv + bv.z);
    o.w = f2bf(a3 * inv + bv.w);
    *reinterpret_cast<ushort4*>(out1 + (size_t)n * H1DIM + c) = o;
}

// ---- GraphNorm stats (bf16 input) ---------------------------------------
__global__ void stats_kernel(const u16* __restrict__ out1, float* __restrict__ gsum,
                             float* __restrict__ gsum2)
{
    int t = threadIdx.x;       // 256; 4 channels each
    int c = t * 4;
    int r0 = blockIdx.x * 64;
    float s0 = 0, s1 = 0, s2 = 0, s3 = 0, q0 = 0, q1 = 0, q2 = 0, q3 = 0;
    for (int i = 0; i < 64; i++) {
        int r = r0 + i;
        if (r >= NNODES) break;
        ushort4 u = *reinterpret_cast<const ushort4*>(out1 + (size_t)r * H1DIM + c);
        float vx = bf2f(u.x), vy = bf2f(u.y), vz = bf2f(u.z), vw = bf2f(u.w);
        s0 += vx; q0 += vx * vx;
        s1 += vy; q1 += vy * vy;
        s2 += vz; q2 += vz * vz;
        s3 += vw; q3 += vw * vw;
    }
    atomicAdd(&gsum[c + 0], s0); atomicAdd(&gsum2[c + 0], q0);
    atomicAdd(&gsum[c + 1], s1); atomicAdd(&gsum2[c + 1], q1);
    atomicAdd(&gsum[c + 2], s2); atomicAdd(&gsum2[c + 2], q2);
    atomicAdd(&gsum[c + 3], s3); atomicAdd(&gsum2[c + 3], q3);
}

__global__ void norm_params_kernel(const float* __restrict__ gsum, const float* __restrict__ gsum2,
                                   const float* __restrict__ w, const float* __restrict__ b,
                                   const float* __restrict__ ms, float* __restrict__ scale,
                                   float* __restrict__ shift)
{
    int c = blockIdx.x * blockDim.x + threadIdx.x;
    if (c >= H1DIM) return;
    const float invN = 1.0f / (float)NNODES;
    float mean = gsum[c] * invN;
    float ex2  = gsum2[c] * invN;
    float msv  = ms[c];
    float var  = ex2 - 2.f * msv * mean * mean + msv * msv * mean * mean;
    float sc   = w[c] * rsqrtf(fmaxf(var, 0.f) + GNEPS);
    scale[c] = sc;
    shift[c] = b[c] - sc * msv * mean;
}

// ---- in-place: out1 = bf16(relu(scale*out1+shift)) ----------------------
__global__ void hn_kernel(u16* __restrict__ out1, const float* __restrict__ scale,
                          const float* __restrict__ shift)
{
    int i = blockIdx.x * blockDim.x + threadIdx.x;
    size_t idx = (size_t)i * 4;
    if (idx >= (size_t)NNODES * H1DIM) return;
    int c = (int)(idx & (H1DIM - 1));
    ushort4 u  = *reinterpret_cast<const ushort4*>(out1 + idx);
    float4 sc = *reinterpret_cast<const float4*>(scale + c);
    float4 sh = *reinterpret_cast<const float4*>(shift + c);
    ushort4 o;
    o.x = f2bf(fmaxf(0.f, bf2f(u.x) * sc.x + sh.x));
    o.y = f2bf(fmaxf(0.f, bf2f(u.y) * sc.y + sh.y));
    o.z = f2bf(fmaxf(0.f, bf2f(u.z) * sc.z + sh.z));
    o.w = f2bf(fmaxf(0.f, bf2f(u.w) * sc.w + sh.w));
    *reinterpret_cast<ushort4*>(out1 + idx) = o;
}

// ---- layer-2 aggregation, one wave per dst; h2 bf16; dual-dtype out -----
__global__ void agg2_kernel(const int* __restrict__ offs, const int* __restrict__ ssort,
                            const float* __restrict__ als, const float* __restrict__ ald,
                            const u16* __restrict__ h2, const float* __restrict__ b2,
                            const int* __restrict__ fflag, void* __restrict__ outv)
{
    int n = blockIdx.x;
    int t = threadIdx.x;       // 64; 4 channels each
    int c = t * 4;
    int e0 = offs[n], e1 = offs[n + 1];
    float adv = ald[n];

    float m = -1e30f;
    for (int e = e0; e < e1; e++) {
        int s = ssort[e];
        float v = lrelu(als[s] + adv);
        m = fmaxf(m, v);
    }
    float denom = 0.f, a0 = 0.f, a1 = 0.f, a2 = 0.f, a3 = 0.f;
    for (int e = e0; e < e1; e++) {
        int s = ssort[e];
        float v = lrelu(als[s] + adv);
        float w = __expf(v - m);
        denom += w;
        ushort4 hv = *reinterpret_cast<const ushort4*>(h2 + (size_t)s * FOUT + c);
        a0 += w * bf2f(hv.x); a1 += w * bf2f(hv.y);
        a2 += w * bf2f(hv.z); a3 += w * bf2f(hv.w);
    }
    float inv = (denom > 0.f) ? 1.0f / denom : 0.f;
    float4 bv = *reinterpret_cast<const float4*>(b2 + c);
    float r0 = a0 * inv + bv.x;
    float r1 = a1 * inv + bv.y;
    float r2 = a2 * inv + bv.z;
    float r3 = a3 * inv + bv.w;
    if (fflag[0]) {
        ushort4 o;
        o.x = f2bf(r0); o.y = f2bf(r1); o.z = f2bf(r2); o.w = f2bf(r3);
        *reinterpret_cast<ushort4*>((u16*)outv + (size_t)n * FOUT + c) = o;
    } else {
        *reinterpret_cast<float4*>((float*)outv + (size_t)n * FOUT + c) =
            make_float4(r0, r1, r2, r3);
    }
}

// =========================================================================
extern "C" void kernel_launch(void* const* d_in, const int* in_sizes, int n_in,
                              void* d_out, int out_size, void* d_ws, size_t ws_size,
                              hipStream_t stream)
{
    const void* x    = d_in[0];
    const int*  ei   = (const int*)d_in[1];
    const void* W1   = d_in[2];
    const void* as1  = d_in[3];
    const void* ad1  = d_in[4];
    const void* b1   = d_in[5];
    const void* gnw  = d_in[6];
    const void* gnb  = d_in[7];
    const void* gnms = d_in[8];
    const void* W2   = d_in[9];
    const void* as2  = d_in[10];
    const void* ad2  = d_in[11];
    const void* b2   = d_in[12];

    const int NE   = in_sizes[1] / 2;       // 160000
    const int Etot = NE + NNODES;           // 170000

    // ---- workspace carve (256B aligned), total ~53 MB ----
    char* w = (char*)d_ws;
    size_t off = 0;
    auto carve = [&](size_t bytes) -> char* {
        char* p = w + off;
        off = (off + bytes + 255) & ~(size_t)255;
        return p;
    };
    int*   deg    = (int*)carve((size_t)NNODES * 4);
    int*   cursor = (int*)carve((size_t)NNODES * 4);
    float* gsum   = (float*)carve(1024 * 4);
    float* gsum2  = (float*)carve(1024 * 4);
    size_t zero_bytes = off;                        // memset-0 region
    int*   flag   = (int*)carve(256);               // [0]=ei is64
    int*   fflag  = (int*)carve(256);               // [0]=float inputs are bf16
    int*   offs   = (int*)carve((size_t)(NNODES + 1) * 4);
    int*   ssort  = (int*)carve((size_t)Etot * 4);
    u16*   h1buf  = (u16*)carve((size_t)NNODES * H1DIM * 2);   // h1 bf16; reused as h2 bf16
    u16*   out1b  = (u16*)carve((size_t)NNODES * H1DIM * 2);   // agg1 out; normalized in place
    float* al1s   = (float*)carve((size_t)NNODES * HEADS * 4);
    float* al1d   = (float*)carve((size_t)NNODES * HEADS * 4);
    float* al2s   = (float*)carve((size_t)NNODES * 4);
    float* al2d   = (float*)carve((size_t)NNODES * 4);
    float* scale  = (float*)carve(1024 * 4);
    float* shift  = (float*)carve(1024 * 4);
    // canonical GEMM operands (bf16) + small fp32 copies
    u16*   xb    = (u16*)carve((size_t)NNODES * FIN * 2);      // 5.12 MB
    u16*   W1t   = (u16*)carve((size_t)H1DIM * FIN * 2);       // [N=1024][K=256]
    u16*   W2t   = (u16*)carve((size_t)FOUT * H1DIM * 2);      // [N=256][K=1024]
    float* as1f  = (float*)carve(1024 * 4);
    float* ad1f  = (float*)carve(1024 * 4);
    float* b1f   = (float*)carve(1024 * 4);
    float* gnwf  = (float*)carve(1024 * 4);
    float* gnbf  = (float*)carve(1024 * 4);
    float* gnmsf = (float*)carve(1024 * 4);
    float* as2f  = (float*)carve(256 * 4);
    float* ad2f  = (float*)carve(256 * 4);
    float* b2f   = (float*)carve(256 * 4);
    (void)ws_size;

    u16* h2b = h1buf;      // reuse: h1 dead after agg1 (bf16 [N,256] = 5 MB <= 20.5 MB)

    hipMemsetAsync(d_ws, 0, zero_bytes, stream);
    detect_ei_kernel<<<1, 1, 0, stream>>>(ei, flag);
    detect_f_kernel<<<1, 1, 0, stream>>>((const u16*)x, fflag);

    // conversions
    {
        CvtTable tab;
        tab.d[0] = { as1,  as1f,  H1DIM };
        tab.d[1] = { ad1,  ad1f,  H1DIM };
        tab.d[2] = { b1,   b1f,   H1DIM };
        tab.d[3] = { gnw,  gnwf,  H1DIM };
        tab.d[4] = { gnb,  gnbf,  H1DIM };
        tab.d[5] = { gnms, gnmsf, H1DIM };
        tab.d[6] = { as2,  as2f,  FOUT };
        tab.d[7] = { ad2,  ad2f,  FOUT };
        tab.d[8] = { b2,   b2f,   FOUT };
        dim3 grd(1, 9);
        convert_small_kernel<<<grd, 256, 0, stream>>>(tab, fflag);
    }
    cvt_x_kernel<<<(NNODES * FIN / 4 + 255) / 256, 256, 0, stream>>>(x, xb, NNODES * FIN, fflag);
    cvt_wt_kernel<<<(FIN * H1DIM + 255) / 256, 256, 0, stream>>>(W1, W1t, FIN, H1DIM, fflag);
    cvt_wt_kernel<<<(H1DIM * FOUT + 255) / 256, 256, 0, stream>>>(W2, W2t, H1DIM, FOUT, fflag);

    // CSR build
    {
        int nb = (Etot + 255) / 256;
        hist_kernel<<<nb, 256, 0, stream>>>(ei, NE, Etot, flag, deg);
        scan_kernel<<<1, 256, 0, stream>>>(deg, offs);
        scatter_kernel<<<nb, 256, 0, stream>>>(ei, NE, Etot, flag, offs, cursor, ssort);
    }

    // layer 1: h1 = x @ W1  (MFMA bf16)
    {
        dim3 grd(H1DIM / 128, (NNODES + 127) / 128);   // 8 x 79
        mfma_gemm_kernel<<<grd, 256, 0, stream>>>(xb, W1t, h1buf, NNODES, H1DIM, FIN);
    }
    al1_kernel<<<NNODES, 256, 0, stream>>>(h1buf, as1f, ad1f, al1s, al1d);
    agg1_kernel<<<NNODES, 256, 0, stream>>>(offs, ssort, al1s, al1d, h1buf, b1f, out1b);

    // GraphNorm + ReLU (in place on out1b)
    stats_kernel<<<(NNODES + 63) / 64, 256, 0, stream>>>(out1b, gsum, gsum2);
    norm_params_kernel<<<(H1DIM + 255) / 256, 256, 0, stream>>>(gsum, gsum2, gnwf, gnbf, gnmsf, scale, shift);
    hn_kernel<<<(NNODES * H1DIM / 4 + 255) / 256, 256, 0, stream>>>(out1b, scale, shift);

    // layer 2: h2 = hn @ W2 (MFMA bf16, out bf16 into h1buf region)
    {
        dim3 grd(FOUT / 128, (NNODES + 127) / 128);    // 2 x 79
        mfma_gemm_kernel<<<grd, 256, 0, stream>>>(out1b, W2t, h2b, NNODES, FOUT, H1DIM);
    }
    al2_kernel<<<NNODES, 64, 0, stream>>>(h2b, as2f, ad2f, al2s, al2d);
    agg2_kernel<<<NNODES, 64, 0, stream>>>(offs, ssort, al2s, al2d, h2b, b2f, fflag, d_out);
}

// Round 5
// 314.059 us; speedup vs baseline: 1.4779x; 1.0772x over previous
//
#include <hip/hip_runtime.h>
#include <hip/hip_bf16.h>

#define NNODES 10000
#define FIN    256
#define HEADS  4
#define H1DIM  1024
#define FOUT   256
#define NEG    0.2f
#define GNEPS  1e-5f

typedef unsigned short u16;
typedef __attribute__((ext_vector_type(8))) short bf16x8;
typedef __attribute__((ext_vector_type(4))) float f32x4;

__device__ __forceinline__ float bf2f(u16 u) {
    union { unsigned int i; float f; } v; v.i = ((unsigned int)u) << 16; return v.f;
}
__device__ __forceinline__ u16 f2bf(float f) {
    __hip_bfloat16 h = __float2bfloat16(f);
    union { __hip_bfloat16 h; u16 u; } v; v.h = h; return v.u;
}
__device__ __forceinline__ float lrelu(float v) { return v > 0.f ? v : NEG * v; }

// ---- dtype probes (merged) ----------------------------------------------
__global__ void detect_kernel(const int* __restrict__ ei, const u16* __restrict__ x,
                              int* __restrict__ flag, int* __restrict__ fflag)
{
    int or_odd = ei[1] | ei[3] | ei[5] | ei[7] | ei[9] | ei[11];
    flag[0] = (or_odd == 0) ? 1 : 0;
    int sane = 1;
    for (int i = 0; i < 32; i += 2) {
        u16 w = x[i];
        int e = (w >> 7) & 0xFF;
        if (!(w == 0 || w == 0x8000 || (e >= 100 && e <= 150))) sane = 0;
    }
    fflag[0] = sane;   // 1 = bf16 inputs, 0 = fp32 inputs
}

// ---- small fp32 conversions ---------------------------------------------
struct CvtDesc { const void* src; float* dst; int n; };
struct CvtTable { CvtDesc d[9]; };

__global__ void convert_small_kernel(CvtTable tab, const int* __restrict__ fflag)
{
    CvtDesc d = tab.d[blockIdx.y];
    int i4 = (blockIdx.x * blockDim.x + threadIdx.x) * 4;
    if (i4 >= d.n) return;
    if (fflag[0]) {
        ushort4 u = *reinterpret_cast<const ushort4*>((const u16*)d.src + i4);
        *reinterpret_cast<float4*>(d.dst + i4) =
            make_float4(bf2f(u.x), bf2f(u.y), bf2f(u.z), bf2f(u.w));
    } else {
        *reinterpret_cast<float4*>(d.dst + i4) =
            *reinterpret_cast<const float4*>((const float*)d.src + i4);
    }
}

// ---- x -> bf16 ----------------------------------------------------------
__global__ void cvt_x_kernel(const void* __restrict__ src, u16* __restrict__ dst,
                             int n, const int* __restrict__ fflag)
{
    int i4 = (blockIdx.x * blockDim.x + threadIdx.x) * 4;
    if (i4 >= n) return;
    if (fflag[0]) {
        *reinterpret_cast<ushort4*>(dst + i4) =
            *reinterpret_cast<const ushort4*>((const u16*)src + i4);
    } else {
        float4 v = *reinterpret_cast<const float4*>((const float*)src + i4);
        ushort4 o; o.x = f2bf(v.x); o.y = f2bf(v.y); o.z = f2bf(v.z); o.w = f2bf(v.w);
        *reinterpret_cast<ushort4*>(dst + i4) = o;
    }
}

// ---- W [K,N] -> Wt bf16 [N,K] -------------------------------------------
__global__ void cvt_wt_kernel(const void* __restrict__ src, u16* __restrict__ dst,
                              int K, int N, const int* __restrict__ fflag)
{
    int i = blockIdx.x * blockDim.x + threadIdx.x;
    if (i >= K * N) return;
    int k = i / N, n = i - k * N;
    u16 o;
    if (fflag[0]) o = ((const u16*)src)[i];
    else          o = f2bf(((const float*)src)[i]);
    dst[(size_t)n * K + k] = o;
}

// ---- P[j][k] = sum_c W1t[(hd*256+c)][k] * a[hd*256+c];  j: 0..3 src, 4..7 dst
__global__ void pvec_kernel(const u16* __restrict__ W1t, const float* __restrict__ as1f,
                            const float* __restrict__ ad1f, float* __restrict__ P)
{
    int j = blockIdx.x;                 // 0..7
    int hd = j & 3;
    const float* av = (j < 4 ? as1f : ad1f) + hd * FIN;
    int k = threadIdx.x;                // 0..255
    float acc = 0.f;
    for (int c = 0; c < FIN; c++)
        acc += bf2f(W1t[((size_t)(hd * FIN + c)) * FIN + k]) * av[c];
    P[j * FIN + k] = acc;
}

// ---- als1/ald1 = x @ P : one wave per node ------------------------------
__global__ void alsd1_kernel(const u16* __restrict__ xb, const float* __restrict__ P,
                             float* __restrict__ als, float* __restrict__ ald)
{
    int wave = threadIdx.x >> 6, lane = threadIdx.x & 63;
    int n = blockIdx.x * 4 + wave;
    if (n >= NNODES) return;
    ushort4 xv = *reinterpret_cast<const ushort4*>(xb + (size_t)n * FIN + lane * 4);
    float x0 = bf2f(xv.x), x1 = bf2f(xv.y), x2 = bf2f(xv.z), x3 = bf2f(xv.w);
    float r[8];
#pragma unroll
    for (int j = 0; j < 8; j++) {
        float4 p = *reinterpret_cast<const float4*>(P + j * FIN + lane * 4);
        r[j] = x0 * p.x + x1 * p.y + x2 * p.z + x3 * p.w;
    }
#pragma unroll
    for (int off = 32; off > 0; off >>= 1)
#pragma unroll
        for (int j = 0; j < 8; j++)
            r[j] += __shfl_xor(r[j], off, 64);
    if (lane == 0) {
        *reinterpret_cast<float4*>(als + n * 4) = make_float4(r[0], r[1], r[2], r[3]);
        *reinterpret_cast<float4*>(ald + n * 4) = make_float4(r[4], r[5], r[6], r[7]);
    }
}

// ---- CSR build ----------------------------------------------------------
__global__ void hist_kernel(const int* __restrict__ ei, int NE, int Etot,
                            const int* __restrict__ flag, int* __restrict__ deg)
{
    int e = blockIdx.x * blockDim.x + threadIdx.x;
    if (e >= Etot) return;
    int is64 = flag[0];
    int dst;
    if (e < NE) dst = is64 ? ei[2 * (NE + e)] : ei[NE + e];
    else        dst = e - NE;
    if ((unsigned)dst >= NNODES) return;
    atomicAdd(&deg[dst], 1);
}

__global__ void scan_kernel(const int* __restrict__ deg, int* __restrict__ offs)
{
    __shared__ int part[256];
    const int N = NNODES;
    const int chunk = 40;
    int t = threadIdx.x;
    int start = t * chunk;
    int s = 0;
    for (int i = 0; i < chunk; i++) { int idx = start + i; if (idx < N) s += deg[idx]; }
    part[t] = s;
    __syncthreads();
    for (int d = 1; d < 256; d <<= 1) {
        int v = (t >= d) ? part[t - d] : 0;
        __syncthreads();
        part[t] += v;
        __syncthreads();
    }
    int run = (t > 0) ? part[t - 1] : 0;
    for (int i = 0; i < chunk; i++) {
        int idx = start + i;
        if (idx <= N) offs[idx] = run;
        if (idx < N)  run += deg[idx];
    }
}

__global__ void scatter_kernel(const int* __restrict__ ei, int NE, int Etot,
                               const int* __restrict__ flag,
                               const int* __restrict__ offs, int* __restrict__ cursor,
                               int* __restrict__ ssort)
{
    int e = blockIdx.x * blockDim.x + threadIdx.x;
    if (e >= Etot) return;
    int is64 = flag[0];
    int src, dst;
    if (e < NE) {
        src = is64 ? ei[2 * e] : ei[e];
        dst = is64 ? ei[2 * (NE + e)] : ei[NE + e];
    } else {
        src = dst = e - NE;
    }
    if ((unsigned)dst >= NNODES) return;
    if ((unsigned)src >= NNODES) src = 0;
    int pos = offs[dst] + atomicAdd(&cursor[dst], 1);
    ssort[pos] = src;
}

// ---- agg_x: z[hd][n][0:256] = softmax-weighted sum of x[src]; one wave/dst
__global__ void agg_x_kernel(const int* __restrict__ offs, const int* __restrict__ ssort,
                             const float* __restrict__ als, const float* __restrict__ ald,
                             const u16* __restrict__ xb, u16* __restrict__ zbuf)
{
    const int n = blockIdx.x;
    const int lane = threadIdx.x;    // 64
    const int e0 = offs[n], e1 = offs[n + 1];
    float4 adv = *reinterpret_cast<const float4*>(ald + n * 4);

    // pass 1: per-head max
    float m0 = -1e30f, m1 = -1e30f, m2 = -1e30f, m3 = -1e30f;
    for (int e = e0 + lane; e < e1; e += 64) {
        int s = ssort[e];
        float4 av = *reinterpret_cast<const float4*>(als + s * 4);
        m0 = fmaxf(m0, lrelu(av.x + adv.x));
        m1 = fmaxf(m1, lrelu(av.y + adv.y));
        m2 = fmaxf(m2, lrelu(av.z + adv.z));
        m3 = fmaxf(m3, lrelu(av.w + adv.w));
    }
#pragma unroll
    for (int off = 32; off > 0; off >>= 1) {
        m0 = fmaxf(m0, __shfl_xor(m0, off, 64));
        m1 = fmaxf(m1, __shfl_xor(m1, off, 64));
        m2 = fmaxf(m2, __shfl_xor(m2, off, 64));
        m3 = fmaxf(m3, __shfl_xor(m3, off, 64));
    }

    __shared__ float wlds[128][4];
    float d0 = 0, d1 = 0, d2 = 0, d3 = 0;
    float a[4][4];
#pragma unroll
    for (int h = 0; h < 4; h++)
#pragma unroll
        for (int c = 0; c < 4; c++) a[h][c] = 0.f;

    for (int cs = e0; cs < e1; cs += 128) {
        int ce = min(cs + 128, e1);
        for (int e = cs + lane; e < ce; e += 64) {
            int s = ssort[e];
            float4 av = *reinterpret_cast<const float4*>(als + s * 4);
            float w0 = __expf(lrelu(av.x + adv.x) - m0);
            float w1 = __expf(lrelu(av.y + adv.y) - m1);
            float w2 = __expf(lrelu(av.z + adv.z) - m2);
            float w3 = __expf(lrelu(av.w + adv.w) - m3);
            *reinterpret_cast<float4*>(&wlds[e - cs][0]) = make_float4(w0, w1, w2, w3);
            d0 += w0; d1 += w1; d2 += w2; d3 += w3;
        }
        __syncthreads();
        for (int ee = cs; ee < ce; ee++) {
            int s = ssort[ee];
            float4 w = *reinterpret_cast<const float4*>(&wlds[ee - cs][0]);
            ushort4 xv = *reinterpret_cast<const ushort4*>(xb + (size_t)s * FIN + lane * 4);
            float x0 = bf2f(xv.x), x1 = bf2f(xv.y), x2 = bf2f(xv.z), x3 = bf2f(xv.w);
            a[0][0] += w.x * x0; a[0][1] += w.x * x1; a[0][2] += w.x * x2; a[0][3] += w.x * x3;
            a[1][0] += w.y * x0; a[1][1] += w.y * x1; a[1][2] += w.y * x2; a[1][3] += w.y * x3;
            a[2][0] += w.z * x0; a[2][1] += w.z * x1; a[2][2] += w.z * x2; a[2][3] += w.z * x3;
            a[3][0] += w.w * x0; a[3][1] += w.w * x1; a[3][2] += w.w * x2; a[3][3] += w.w * x3;
        }
        __syncthreads();
    }
#pragma unroll
    for (int off = 32; off > 0; off >>= 1) {
        d0 += __shfl_xor(d0, off, 64);
        d1 += __shfl_xor(d1, off, 64);
        d2 += __shfl_xor(d2, off, 64);
        d3 += __shfl_xor(d3, off, 64);
    }
    float inv0 = d0 > 0.f ? 1.f / d0 : 0.f;
    float inv1 = d1 > 0.f ? 1.f / d1 : 0.f;
    float inv2 = d2 > 0.f ? 1.f / d2 : 0.f;
    float inv3 = d3 > 0.f ? 1.f / d3 : 0.f;
    float invs[4] = {inv0, inv1, inv2, inv3};
#pragma unroll
    for (int h = 0; h < 4; h++) {
        ushort4 o;
        o.x = f2bf(a[h][0] * invs[h]);
        o.y = f2bf(a[h][1] * invs[h]);
        o.z = f2bf(a[h][2] * invs[h]);
        o.w = f2bf(a[h][3] * invs[h]);
        *reinterpret_cast<ushort4*>(zbuf + (size_t)h * NNODES * FIN + (size_t)n * FIN + lane * 4) = o;
    }
}

// ---- MFMA GEMM template --------------------------------------------------
// C[M,N]bf16 = A[M,K]bf16 @ Bt[N,K]^T; 128xBN tile, 4 waves (2x2), per-wave 64x(BN/2)
// NORM_A: apply relu(scale*a+shift) to A during staging; BIAS: add bias[zc+col].
#define LDS_STRIDE 40
template<int BN, bool NORM_A, bool BIAS>
__global__ void __launch_bounds__(256, 2)
mfma_gemm(const u16* __restrict__ A, const u16* __restrict__ Bt,
          u16* __restrict__ C, const float* __restrict__ bias,
          const float* __restrict__ nscale, const float* __restrict__ nshift,
          int M, int K, int ldc, long aZOff, long bZOff, int cZOff)
{
    constexpr int NI = BN / 32;           // frags per wave in N
    __shared__ u16 Alds[128 * LDS_STRIDE];
    __shared__ u16 Blds[BN * LDS_STRIDE];

    const u16* Az = A + (long)blockIdx.z * aZOff;
    const u16* Bz = Bt + (long)blockIdx.z * bZOff;
    const int zc = blockIdx.z * cZOff;

    const int tid  = threadIdx.x;
    const int lane = tid & 63;
    const int wave = tid >> 6;
    const int wm = wave >> 1, wn = wave & 1;
    const int l15 = lane & 15, quad = lane >> 4;
    const int n0 = blockIdx.x * BN;
    const int m0 = blockIdx.y * 128;

    f32x4 acc[4][NI];
#pragma unroll
    for (int i = 0; i < 4; i++)
#pragma unroll
        for (int j = 0; j < NI; j++) acc[i][j] = (f32x4){0.f, 0.f, 0.f, 0.f};

    for (int kt = 0; kt < K; kt += 32) {
        __syncthreads();
        constexpr int GROUPS = 512 + BN * 4;
#pragma unroll
        for (int i = 0; i < GROUPS / 256; i++) {
            int g = i * 256 + tid;
            if (g < 512) {
                int row = g >> 2, col = (g & 3) * 8;
                int gr = m0 + row;
                uint4 av = make_uint4(0u, 0u, 0u, 0u);
                if (gr < M) av = *reinterpret_cast<const uint4*>(Az + (size_t)gr * K + kt + col);
                if (NORM_A) {
                    int kg = kt + col;
                    float4 s0 = *reinterpret_cast<const float4*>(nscale + kg);
                    float4 s1 = *reinterpret_cast<const float4*>(nscale + kg + 4);
                    float4 h0 = *reinterpret_cast<const float4*>(nshift + kg);
                    float4 h1 = *reinterpret_cast<const float4*>(nshift + kg + 4);
                    float sc[8] = {s0.x, s0.y, s0.z, s0.w, s1.x, s1.y, s1.z, s1.w};
                    float sh[8] = {h0.x, h0.y, h0.z, h0.w, h1.x, h1.y, h1.z, h1.w};
                    u16* pv = reinterpret_cast<u16*>(&av);
#pragma unroll
                    for (int j = 0; j < 8; j++)
                        pv[j] = f2bf(fmaxf(0.f, bf2f(pv[j]) * sc[j] + sh[j]));
                }
                *reinterpret_cast<uint4*>(&Alds[row * LDS_STRIDE + col]) = av;
            } else {
                int gb = g - 512;
                int row = gb >> 2, col = (gb & 3) * 8;
                uint4 bv = *reinterpret_cast<const uint4*>(Bz + (size_t)(n0 + row) * K + kt + col);
                *reinterpret_cast<uint4*>(&Blds[row * LDS_STRIDE + col]) = bv;
            }
        }
        __syncthreads();

        bf16x8 a_frag[4], b_frag[NI];
#pragma unroll
        for (int mi = 0; mi < 4; mi++)
            a_frag[mi] = *reinterpret_cast<const bf16x8*>(
                &Alds[(wm * 64 + mi * 16 + l15) * LDS_STRIDE + quad * 8]);
#pragma unroll
        for (int ni = 0; ni < NI; ni++)
            b_frag[ni] = *reinterpret_cast<const bf16x8*>(
                &Blds[(wn * (BN / 2) + ni * 16 + l15) * LDS_STRIDE + quad * 8]);
#pragma unroll
        for (int mi = 0; mi < 4; mi++)
#pragma unroll
            for (int ni = 0; ni < NI; ni++)
                acc[mi][ni] = __builtin_amdgcn_mfma_f32_16x16x32_bf16(
                    a_frag[mi], b_frag[ni], acc[mi][ni], 0, 0, 0);
    }

    // epilogue: C/D layout col=lane&15, row=quad*4+reg
#pragma unroll
    for (int mi = 0; mi < 4; mi++) {
#pragma unroll
        for (int r = 0; r < 4; r++) {
            int row = m0 + wm * 64 + mi * 16 + quad * 4 + r;
            if (row >= M) continue;
#pragma unroll
            for (int ni = 0; ni < NI; ni++) {
                int col = n0 + wn * (BN / 2) + ni * 16 + l15;
                float v = acc[mi][ni][r];
                if (BIAS) v += bias[zc + col];
                C[(size_t)row * ldc + zc + col] = f2bf(v);
            }
        }
    }
}

// ---- GraphNorm stats (bf16 input) ---------------------------------------
__global__ void stats_kernel(const u16* __restrict__ out1, float* __restrict__ gsum,
                             float* __restrict__ gsum2)
{
    int t = threadIdx.x;
    int c = t * 4;
    int r0 = blockIdx.x * 64;
    float s0 = 0, s1 = 0, s2 = 0, s3 = 0, q0 = 0, q1 = 0, q2 = 0, q3 = 0;
    for (int i = 0; i < 64; i++) {
        int r = r0 + i;
        if (r >= NNODES) break;
        ushort4 u = *reinterpret_cast<const ushort4*>(out1 + (size_t)r * H1DIM + c);
        float vx = bf2f(u.x), vy = bf2f(u.y), vz = bf2f(u.z), vw = bf2f(u.w);
        s0 += vx; q0 += vx * vx;
        s1 += vy; q1 += vy * vy;
        s2 += vz; q2 += vz * vz;
        s3 += vw; q3 += vw * vw;
    }
    atomicAdd(&gsum[c + 0], s0); atomicAdd(&gsum2[c + 0], q0);
    atomicAdd(&gsum[c + 1], s1); atomicAdd(&gsum2[c + 1], q1);
    atomicAdd(&gsum[c + 2], s2); atomicAdd(&gsum2[c + 2], q2);
    atomicAdd(&gsum[c + 3], s3); atomicAdd(&gsum2[c + 3], q3);
}

__global__ void norm_params_kernel(const float* __restrict__ gsum, const float* __restrict__ gsum2,
                                   const float* __restrict__ w, const float* __restrict__ b,
                                   const float* __restrict__ ms, float* __restrict__ scale,
                                   float* __restrict__ shift)
{
    int c = blockIdx.x * blockDim.x + threadIdx.x;
    if (c >= H1DIM) return;
    const float invN = 1.0f / (float)NNODES;
    float mean = gsum[c] * invN;
    float ex2  = gsum2[c] * invN;
    float msv  = ms[c];
    float var  = ex2 - 2.f * msv * mean * mean + msv * msv * mean * mean;
    float sc   = w[c] * rsqrtf(fmaxf(var, 0.f) + GNEPS);
    scale[c] = sc;
    shift[c] = b[c] - sc * msv * mean;
}

// ---- al2 projections (h2 bf16) ------------------------------------------
__global__ void al2_kernel(const u16* __restrict__ h2, const float* __restrict__ as,
                           const float* __restrict__ ad, float* __restrict__ als,
                           float* __restrict__ ald)
{
    int n = blockIdx.x;
    int t = threadIdx.x;          // 64
    int c = t * 4;
    ushort4 u = *reinterpret_cast<const ushort4*>(h2 + (size_t)n * FOUT + c);
    float4 av = *reinterpret_cast<const float4*>(as + c);
    float4 dv = *reinterpret_cast<const float4*>(ad + c);
    float v0 = bf2f(u.x), v1 = bf2f(u.y), v2 = bf2f(u.z), v3 = bf2f(u.w);
    float ps = v0 * av.x + v1 * av.y + v2 * av.z + v3 * av.w;
    float pd = v0 * dv.x + v1 * dv.y + v2 * dv.z + v3 * dv.w;
#pragma unroll
    for (int off = 32; off > 0; off >>= 1) {
        ps += __shfl_down(ps, off, 64);
        pd += __shfl_down(pd, off, 64);
    }
    if (t == 0) { als[n] = ps; ald[n] = pd; }
}

// ---- layer-2 aggregation, one wave per dst, single-exp ------------------
__global__ void agg2_kernel(const int* __restrict__ offs, const int* __restrict__ ssort,
                            const float* __restrict__ als, const float* __restrict__ ald,
                            const u16* __restrict__ h2, const float* __restrict__ b2,
                            const int* __restrict__ fflag, void* __restrict__ outv)
{
    const int n = blockIdx.x;
    const int lane = threadIdx.x;    // 64
    const int e0 = offs[n], e1 = offs[n + 1];
    float adv = ald[n];

    float m = -1e30f;
    for (int e = e0 + lane; e < e1; e += 64) {
        int s = ssort[e];
        m = fmaxf(m, lrelu(als[s] + adv));
    }
#pragma unroll
    for (int off = 32; off > 0; off >>= 1)
        m = fmaxf(m, __shfl_xor(m, off, 64));

    __shared__ float wlds[128];
    float d = 0.f, a0 = 0.f, a1 = 0.f, a2 = 0.f, a3 = 0.f;
    for (int cs = e0; cs < e1; cs += 128) {
        int ce = min(cs + 128, e1);
        for (int e = cs + lane; e < ce; e += 64) {
            int s = ssort[e];
            float w = __expf(lrelu(als[s] + adv) - m);
            wlds[e - cs] = w;
            d += w;
        }
        __syncthreads();
        for (int ee = cs; ee < ce; ee++) {
            int s = ssort[ee];
            float w = wlds[ee - cs];
            ushort4 hv = *reinterpret_cast<const ushort4*>(h2 + (size_t)s * FOUT + lane * 4);
            a0 += w * bf2f(hv.x); a1 += w * bf2f(hv.y);
            a2 += w * bf2f(hv.z); a3 += w * bf2f(hv.w);
        }
        __syncthreads();
    }
#pragma unroll
    for (int off = 32; off > 0; off >>= 1)
        d += __shfl_xor(d, off, 64);
    float inv = d > 0.f ? 1.f / d : 0.f;
    int c = lane * 4;
    float4 bv = *reinterpret_cast<const float4*>(b2 + c);
    float r0 = a0 * inv + bv.x;
    float r1 = a1 * inv + bv.y;
    float r2 = a2 * inv + bv.z;
    float r3 = a3 * inv + bv.w;
    if (fflag[0]) {
        ushort4 o;
        o.x = f2bf(r0); o.y = f2bf(r1); o.z = f2bf(r2); o.w = f2bf(r3);
        *reinterpret_cast<ushort4*>((u16*)outv + (size_t)n * FOUT + c) = o;
    } else {
        *reinterpret_cast<float4*>((float*)outv + (size_t)n * FOUT + c) =
            make_float4(r0, r1, r2, r3);
    }
}

// =========================================================================
extern "C" void kernel_launch(void* const* d_in, const int* in_sizes, int n_in,
                              void* d_out, int out_size, void* d_ws, size_t ws_size,
                              hipStream_t stream)
{
    const void* x    = d_in[0];
    const int*  ei   = (const int*)d_in[1];
    const void* W1   = d_in[2];
    const void* as1  = d_in[3];
    const void* ad1  = d_in[4];
    const void* b1   = d_in[5];
    const void* gnw  = d_in[6];
    const void* gnb  = d_in[7];
    const void* gnms = d_in[8];
    const void* W2   = d_in[9];
    const void* as2  = d_in[10];
    const void* ad2  = d_in[11];
    const void* b2   = d_in[12];

    const int NE   = in_sizes[1] / 2;       // 160000
    const int Etot = NE + NNODES;           // 170000

    // ---- workspace carve (256B aligned) ----
    char* w = (char*)d_ws;
    size_t off = 0;
    auto carve = [&](size_t bytes) -> char* {
        char* p = w + off;
        off = (off + bytes + 255) & ~(size_t)255;
        return p;
    };
    int*   deg    = (int*)carve((size_t)NNODES * 4);
    int*   cursor = (int*)carve((size_t)NNODES * 4);
    float* gsum   = (float*)carve(1024 * 4);
    float* gsum2  = (float*)carve(1024 * 4);
    size_t zero_bytes = off;                        // memset-0 region
    int*   flag   = (int*)carve(256);               // [0]=ei is64
    int*   fflag  = (int*)carve(256);               // [0]=float inputs are bf16
    int*   offs   = (int*)carve((size_t)(NNODES + 1) * 4);
    int*   ssort  = (int*)carve((size_t)Etot * 4);
    u16*   zbuf   = (u16*)carve((size_t)HEADS * NNODES * FIN * 2);  // 20.5 MB; reused as h2
    u16*   out1b  = (u16*)carve((size_t)NNODES * H1DIM * 2);        // 20.5 MB
    float* al1s   = (float*)carve((size_t)NNODES * HEADS * 4);
    float* al1d   = (float*)carve((size_t)NNODES * HEADS * 4);
    float* al2s   = (float*)carve((size_t)NNODES * 4);
    float* al2d   = (float*)carve((size_t)NNODES * 4);
    float* scale  = (float*)carve(1024 * 4);
    float* shift  = (float*)carve(1024 * 4);
    u16*   xb     = (u16*)carve((size_t)NNODES * FIN * 2);
    u16*   W1t    = (u16*)carve((size_t)H1DIM * FIN * 2);
    u16*   W2t    = (u16*)carve((size_t)FOUT * H1DIM * 2);
    float* Pm     = (float*)carve(8 * FIN * 4);
    float* as1f   = (float*)carve(1024 * 4);
    float* ad1f   = (float*)carve(1024 * 4);
    float* b1f    = (float*)carve(1024 * 4);
    float* gnwf   = (float*)carve(1024 * 4);
    float* gnbf   = (float*)carve(1024 * 4);
    float* gnmsf  = (float*)carve(1024 * 4);
    float* as2f   = (float*)carve(256 * 4);
    float* ad2f   = (float*)carve(256 * 4);
    float* b2f    = (float*)carve(256 * 4);
    (void)ws_size;

    u16* h2b = zbuf;    // reuse: z dead after zgemm; h2 bf16 [10000,256] = 5 MB

    hipMemsetAsync(d_ws, 0, zero_bytes, stream);
    detect_kernel<<<1, 1, 0, stream>>>(ei, (const u16*)x, flag, fflag);

    // conversions
    {
        CvtTable tab;
        tab.d[0] = { as1,  as1f,  H1DIM };
        tab.d[1] = { ad1,  ad1f,  H1DIM };
        tab.d[2] = { b1,   b1f,   H1DIM };
        tab.d[3] = { gnw,  gnwf,  H1DIM };
        tab.d[4] = { gnb,  gnbf,  H1DIM };
        tab.d[5] = { gnms, gnmsf, H1DIM };
        tab.d[6] = { as2,  as2f,  FOUT };
        tab.d[7] = { ad2,  ad2f,  FOUT };
        tab.d[8] = { b2,   b2f,   FOUT };
        dim3 grd(1, 9);
        convert_small_kernel<<<grd, 256, 0, stream>>>(tab, fflag);
    }
    cvt_x_kernel<<<(NNODES * FIN / 4 + 255) / 256, 256, 0, stream>>>(x, xb, NNODES * FIN, fflag);
    cvt_wt_kernel<<<(FIN * H1DIM + 255) / 256, 256, 0, stream>>>(W1, W1t, FIN, H1DIM, fflag);
    cvt_wt_kernel<<<(H1DIM * FOUT + 255) / 256, 256, 0, stream>>>(W2, W2t, H1DIM, FOUT, fflag);

    // attention projections via rank-1 trick: P = W1^T a ; als/ald = x @ P
    pvec_kernel<<<8, 256, 0, stream>>>(W1t, as1f, ad1f, Pm);
    alsd1_kernel<<<(NNODES + 3) / 4, 256, 0, stream>>>(xb, Pm, al1s, al1d);

    // CSR build
    {
        int nb = (Etot + 255) / 256;
        hist_kernel<<<nb, 256, 0, stream>>>(ei, NE, Etot, flag, deg);
        scan_kernel<<<1, 256, 0, stream>>>(deg, offs);
        scatter_kernel<<<nb, 256, 0, stream>>>(ei, NE, Etot, flag, offs, cursor, ssort);
    }

    // layer 1: aggregate x with softmax weights -> z (per-head), then z @ W1_hd
    agg_x_kernel<<<NNODES, 64, 0, stream>>>(offs, ssort, al1s, al1d, xb, zbuf);
    {
        dim3 grd(FIN / 128, (NNODES + 127) / 128, HEADS);   // 2 x 79 x 4
        mfma_gemm<128, false, true><<<grd, 256, 0, stream>>>(
            zbuf, W1t, out1b, b1f, nullptr, nullptr,
            NNODES, FIN, H1DIM,
            (long)NNODES * FIN, (long)FIN * FIN, FIN);
    }

    // GraphNorm params
    stats_kernel<<<(NNODES + 63) / 64, 256, 0, stream>>>(out1b, gsum, gsum2);
    norm_params_kernel<<<(H1DIM + 255) / 256, 256, 0, stream>>>(gsum, gsum2, gnwf, gnbf, gnmsf, scale, shift);

    // layer 2: h2 = relu(norm(out1)) @ W2 (norm fused into A-staging)
    {
        dim3 grd(FOUT / 64, (NNODES + 127) / 128, 1);       // 4 x 79
        mfma_gemm<64, true, false><<<grd, 256, 0, stream>>>(
            out1b, W2t, h2b, nullptr, scale, shift,
            NNODES, H1DIM, FOUT, 0L, 0L, 0);
    }
    al2_kernel<<<NNODES, 64, 0, stream>>>(h2b, as2f, ad2f, al2s, al2d);
    agg2_kernel<<<NNODES, 64, 0, stream>>>(offs, ssort, al2s, al2d, h2b, b2f, fflag, d_out);
}